// Round 2
// baseline (330.317 us; speedup 1.0000x reference)
//
#include <hip/hip_runtime.h>
#include <math.h>
#include <stdint.h>

// UpsampleFlow3: fused exact 5-NN + softmax(-dist) + weighted flow sum.
// B=4, N=16384, M=4096, K=5, fp32.
//
// Round-2 structure (from rocprof: 40 VALU/candidate due to if-converted
// insert ladder; occupancy capped at 25% by 64KB LDS point cache):
//  - two-pass top-k: pass1 = branchless value-only min/max bubble (15 VALU/cand),
//    pass2 = re-scan collecting (d2,idx) <= 5th-smallest into tiny LDS lists.
//  - no LDS point cache: candidates read via wave-uniform loads from a
//    precomputed float4(x,y,z,|p|^2) array in d_ws (L2-resident, scalar-load
//    friendly). LDS = 36.8KB -> 4 blocks/CU -> 32 waves/CU.

#define KNN 5
#define SLICES 8                 // waves per block, each scans M/SLICES candidates
#define BLOCK (SLICES * 64)      // 512 threads
#define CAP 6                    // per-(wave,lane) pass-2 list capacity

typedef unsigned long long u64;
typedef unsigned int u32;

__device__ __forceinline__ float get_inv_sigma(const int* __restrict__ rf) {
    // resol_factor: Python int -> int32 array; defensively accept fp32 bits too.
    const int ri = rf[0];
    const float sigma = (ri >= 1 && ri <= 1000000) ? (float)ri : __int_as_float(ri);
    return 1.0f / sigma;         // INITIAL_RADIUS = 1.0
}

__global__ __launch_bounds__(256)
void prep_kernel(const float* __restrict__ sxyz, const int* __restrict__ rf,
                 float4* __restrict__ pts, int M, int total) {
    const int t = blockIdx.x * 256 + threadIdx.x;
    if (t >= total) return;
    const float inv = get_inv_sigma(rf);
    const int b = t / M, m = t - b * M;
    const float* sb = sxyz + (size_t)b * 3 * M;
    const float x = sb[m] * inv;
    const float y = sb[M + m] * inv;
    const float z = sb[2 * M + m] * inv;
    pts[t] = make_float4(x, y, z, fmaf(x, x, fmaf(y, y, z * z)));
}

template <bool USE_PTS>
__global__ __launch_bounds__(BLOCK, 8)
void knn_kernel(const float* __restrict__ xyz,
                const float* __restrict__ sxyz,
                const float* __restrict__ sflow,
                const int* __restrict__ rf,
                const float4* __restrict__ pts,
                float* __restrict__ out,
                int N, int M, int blocksPerBatch) {
    __shared__ float svals[SLICES * KNN * 64];   // [w][k][lane]  10.0 KB
    __shared__ u64   lists[SLICES * 64 * CAP];   // [w][lane][i]  24.0 KB
    __shared__ int   cnts[SLICES * 64];          //                2.0 KB

    const int tid  = threadIdx.x;
    const int lane = tid & 63;
    const int wid  = tid >> 6;
    const int b    = blockIdx.x / blocksPerBatch;
    const int n    = (blockIdx.x % blocksPerBatch) * 64 + lane;   // N % 64 == 0

    const float inv = get_inv_sigma(rf);
    const float* qb = xyz + (size_t)b * 3 * N;
    const float qx = qb[n] * inv;
    const float qy = qb[N + n] * inv;
    const float qz = qb[2 * N + n] * inv;
    const float qq = qx * qx + qy * qy + qz * qz;

    const int CH = M / SLICES;       // 512
    const int j0 = wid * CH;

    const float4* P = nullptr;
    const float*  sb = nullptr;
    if constexpr (USE_PTS) P = pts + (size_t)b * M + j0;
    else                   sb = sxyz + (size_t)b * 3 * M;

    // ---------- pass 1: 5 smallest distance VALUES (branchless bubble) ----------
    float e0 = 1e30f, e1 = 1e30f, e2 = 1e30f, e3 = 1e30f, e4 = 1e30f;
#pragma unroll 4
    for (int j = 0; j < CH; ++j) {
        float px, py, pz, pw;
        if constexpr (USE_PTS) {
            const float4 p = P[j];               // wave-uniform address
            px = p.x; py = p.y; pz = p.z; pw = p.w;
        } else {
            px = sb[j0 + j] * inv;
            py = sb[M + j0 + j] * inv;
            pz = sb[2 * M + j0 + j] * inv;
            pw = fmaf(px, px, fmaf(py, py, pz * pz));
        }
        float t = qx * px;
        t = fmaf(qy, py, t);
        t = fmaf(qz, pz, t);
        const float dc = fmaxf(fmaf(-2.0f, t, qq + pw), 1e-12f);
        float c = dc, m;
        m = fminf(e0, c); c = fmaxf(e0, c); e0 = m;
        m = fminf(e1, c); c = fmaxf(e1, c); e1 = m;
        m = fminf(e2, c); c = fmaxf(e2, c); e2 = m;
        m = fminf(e3, c); c = fmaxf(e3, c); e3 = m;
        e4 = fminf(e4, c);
    }
    svals[(wid * KNN + 0) * 64 + lane] = e0;
    svals[(wid * KNN + 1) * 64 + lane] = e1;
    svals[(wid * KNN + 2) * 64 + lane] = e2;
    svals[(wid * KNN + 3) * 64 + lane] = e3;
    svals[(wid * KNN + 4) * 64 + lane] = e4;
    __syncthreads();

    // ---------- global 5th-smallest value for this lane's query ----------
    float t0 = 1e30f, t1 = 1e30f, t2 = 1e30f, t3 = 1e30f, t4 = 1e30f;
#pragma unroll
    for (int w = 0; w < SLICES; ++w) {
#pragma unroll
        for (int k = 0; k < KNN; ++k) {
            float c = svals[(w * KNN + k) * 64 + lane], m;
            m = fminf(t0, c); c = fmaxf(t0, c); t0 = m;
            m = fminf(t1, c); c = fmaxf(t1, c); t1 = m;
            m = fminf(t2, c); c = fmaxf(t2, c); t2 = m;
            m = fminf(t3, c); c = fmaxf(t3, c); t3 = m;
            t4 = fminf(t4, c);
        }
    }
    // epsilon guard against 1-ulp scheduling differences between passes;
    // extra inclusions are harmless (final ladder keeps exact best 5).
    const float thr = t4 * (1.0f + 2e-6f);

    // ---------- pass 2: collect (d2,idx) <= thr, bit-identical arithmetic ----------
    int cnt = 0;
#pragma unroll 4
    for (int j = 0; j < CH; ++j) {
        float px, py, pz, pw;
        if constexpr (USE_PTS) {
            const float4 p = P[j];
            px = p.x; py = p.y; pz = p.z; pw = p.w;
        } else {
            px = sb[j0 + j] * inv;
            py = sb[M + j0 + j] * inv;
            pz = sb[2 * M + j0 + j] * inv;
            pw = fmaf(px, px, fmaf(py, py, pz * pz));
        }
        float t = qx * px;
        t = fmaf(qy, py, t);
        t = fmaf(qz, pz, t);
        const float dc = fmaxf(fmaf(-2.0f, t, qq + pw), 1e-12f);
        if (dc <= thr && cnt < CAP) {
            // key sorts by (distance, then lowest index) = jax top_k tie rule
            lists[(wid * 64 + lane) * CAP + cnt] =
                ((u64)__float_as_uint(dc) << 32) | (u32)(j0 + j);
            cnt++;
        }
    }
    cnts[wid * 64 + lane] = cnt;
    __syncthreads();

    // ---------- wave 0: merge lists -> top-5, softmax, gather flow, store ----------
    if (wid == 0) {
        u64 k0 = ~0ULL, k1 = ~0ULL, k2 = ~0ULL, k3 = ~0ULL, k4 = ~0ULL;
        for (int w = 0; w < SLICES; ++w) {
            const int c = cnts[w * 64 + lane];
#pragma unroll
            for (int i = 0; i < CAP; ++i) {
                u64 cc = (i < c) ? lists[(w * 64 + lane) * CAP + i] : ~0ULL;
                u64 lo;
                lo = cc < k0 ? cc : k0;  cc = cc < k0 ? k0 : cc;  k0 = lo;
                lo = cc < k1 ? cc : k1;  cc = cc < k1 ? k1 : cc;  k1 = lo;
                lo = cc < k2 ? cc : k2;  cc = cc < k2 ? k2 : cc;  k2 = lo;
                lo = cc < k3 ? cc : k3;  cc = cc < k3 ? k3 : cc;  k3 = lo;
                k4 = cc < k4 ? cc : k4;
            }
        }

        const float d0 = sqrtf(__uint_as_float((u32)(k0 >> 32)));
        const float d1 = sqrtf(__uint_as_float((u32)(k1 >> 32)));
        const float d2 = sqrtf(__uint_as_float((u32)(k2 >> 32)));
        const float d3 = sqrtf(__uint_as_float((u32)(k3 >> 32)));
        const float d4 = sqrtf(__uint_as_float((u32)(k4 >> 32)));
        const float dmin = d0;  // sorted ascending
        const float w0 = expf(dmin - d0);
        const float w1 = expf(dmin - d1);
        const float w2 = expf(dmin - d2);
        const float w3 = expf(dmin - d3);
        const float w4 = expf(dmin - d4);
        const float inv_wsum = 1.0f / (w0 + w1 + w2 + w3 + w4);

        const int i0 = (int)(u32)k0, i1 = (int)(u32)k1, i2 = (int)(u32)k2,
                  i3 = (int)(u32)k3, i4 = (int)(u32)k4;
        const float* fb = sflow + (size_t)b * 3 * M;
        float ax = 0.f, ay = 0.f, az = 0.f;
        ax = fmaf(w0, fb[i0], ax); ay = fmaf(w0, fb[M + i0], ay); az = fmaf(w0, fb[2 * M + i0], az);
        ax = fmaf(w1, fb[i1], ax); ay = fmaf(w1, fb[M + i1], ay); az = fmaf(w1, fb[2 * M + i1], az);
        ax = fmaf(w2, fb[i2], ax); ay = fmaf(w2, fb[M + i2], ay); az = fmaf(w2, fb[2 * M + i2], az);
        ax = fmaf(w3, fb[i3], ax); ay = fmaf(w3, fb[M + i3], ay); az = fmaf(w3, fb[2 * M + i3], az);
        ax = fmaf(w4, fb[i4], ax); ay = fmaf(w4, fb[M + i4], ay); az = fmaf(w4, fb[2 * M + i4], az);

        float* ob = out + (size_t)b * 3 * N;
        ob[n]         = ax * inv_wsum;
        ob[N + n]     = ay * inv_wsum;
        ob[2 * N + n] = az * inv_wsum;
    }
}

extern "C" void kernel_launch(void* const* d_in, const int* in_sizes, int n_in,
                              void* d_out, int out_size, void* d_ws, size_t ws_size,
                              hipStream_t stream) {
    const float* xyz   = (const float*)d_in[0];
    const float* sxyz  = (const float*)d_in[1];
    const float* sflow = (const float*)d_in[2];
    const int*   rf    = (const int*)d_in[3];
    // d_in[4] = K; fixed at 5 (KNN).

    const int B = 4;
    const int N = in_sizes[0] / (3 * B);    // 16384
    const int M = in_sizes[1] / (3 * B);    // 4096
    float* out = (float*)d_out;

    const int blocksPerBatch = N / 64;      // 256
    const dim3 grid(B * blocksPerBatch);    // 1024 blocks = 4/CU exactly
    const dim3 block(BLOCK);

    const size_t need = (size_t)B * M * sizeof(float4);
    if (ws_size >= need) {
        float4* pts = (float4*)d_ws;
        prep_kernel<<<dim3((B * M + 255) / 256), dim3(256), 0, stream>>>(sxyz, rf, pts, M, B * M);
        knn_kernel<true><<<grid, block, 0, stream>>>(xyz, sxyz, sflow, rf, pts, out,
                                                     N, M, blocksPerBatch);
    } else {
        knn_kernel<false><<<grid, block, 0, stream>>>(xyz, sxyz, sflow, rf, nullptr, out,
                                                      N, M, blocksPerBatch);
    }
}

// Round 3
// 252.224 us; speedup vs baseline: 1.3096x; 1.3096x over previous
//
#include <hip/hip_runtime.h>
#include <math.h>
#include <stdint.h>

// UpsampleFlow3: fused exact 5-NN + softmax(-dist) + weighted flow sum.
// B=4, N=16384, M=4096, K=5, fp32.
//
// Round-3 structure (post-mortems: r1 = 40 VALU/cand if-converted ladder,
// r2 = scalar-load theory failed because wid-derived offset is not provably
// uniform; two passes doubled work):
//  - readfirstlane(wid) makes the slice offset SGPR-backed -> candidate
//    loads are s_load_dwordx4 on the scalar pipe (0 VALU / 0 LDS per cand).
//  - rank by d2' = |p|^2 - 2 q.p  (qq added per-lane later; order preserved)
//    -> 4 VALU distance + 23 VALU exact (value,idx) CE ladder = 27/candidate.
//  - 8 M-slices per 64-query group, 8 waves/SIMD, wave 0 merges + epilogue.

#define KNN 5
#define SLICES 8
#define BLOCK (SLICES * 64)       // 512 threads
#define GRP_SHIFT 8               // blocksPerBatch = N/64 = 256 = 1<<8

typedef unsigned int u32;

__device__ __forceinline__ float get_inv_sigma(const int* __restrict__ rf) {
    // resol_factor: Python int -> int32 array; defensively accept fp32 bits too.
    const int ri = rf[0];
    const float sigma = (ri >= 1 && ri <= 1000000) ? (float)ri : __int_as_float(ri);
    return 1.0f / sigma;          // INITIAL_RADIUS = 1.0
}

__global__ __launch_bounds__(256)
void prep_kernel(const float* __restrict__ sxyz, const int* __restrict__ rf,
                 float4* __restrict__ pts, int M, int total) {
    const int t = blockIdx.x * 256 + threadIdx.x;
    if (t >= total) return;
    const float inv = get_inv_sigma(rf);
    const int b = t / M, m = t - b * M;
    const float* sb = sxyz + (size_t)b * 3 * M;
    const float x = sb[m] * inv;
    const float y = sb[M + m] * inv;
    const float z = sb[2 * M + m] * inv;
    pts[t] = make_float4(x, y, z, fmaf(x, x, fmaf(y, y, z * z)));
}

// Compare-exchange: insert candidate (c,ci) into slot (k,ki); larger goes on.
#define CE_FULL(k, ki, c, ci)                          \
    {                                                  \
        const bool sw = (c) < (k);                     \
        const float vmn = fminf(k, c);                 \
        const float vmx = fmaxf(k, c);                 \
        const u32 nki = sw ? (ci) : (ki);              \
        const u32 nci = sw ? (ki) : (ci);              \
        (k) = vmn; (c) = vmx; (ki) = nki; (ci) = nci;  \
    }
#define CE_LAST(k, ki, c, ci)                          \
    {                                                  \
        const bool sw = (c) < (k);                     \
        (ki) = sw ? (ci) : (ki);                       \
        (k) = fminf(k, c);                             \
    }

template <bool USE_PTS>
__global__ __launch_bounds__(BLOCK, 8)
void knn_kernel(const float* __restrict__ xyz,
                const float* __restrict__ sxyz,
                const float* __restrict__ sflow,
                const int* __restrict__ rf,
                const float4* __restrict__ pts,
                float* __restrict__ out,
                int N, int M) {
    __shared__ float sval_d[SLICES * KNN * 64];   // 10 KB
    __shared__ u32   sval_i[SLICES * KNN * 64];   // 10 KB

    const int tid  = threadIdx.x;
    const int lane = tid & 63;
    const int wid  = tid >> 6;
    // readfirstlane: SGPR-backed -> downstream addresses are provably uniform.
    const int swid = __builtin_amdgcn_readfirstlane(wid);
    const int b    = blockIdx.x >> GRP_SHIFT;
    const int grp  = blockIdx.x & ((1 << GRP_SHIFT) - 1);
    const int n    = grp * 64 + lane;             // N % 64 == 0

    const float inv = get_inv_sigma(rf);
    const float* qb = xyz + (size_t)b * 3 * N;
    const float qx = qb[n] * inv;
    const float qy = qb[N + n] * inv;
    const float qz = qb[2 * N + n] * inv;
    const float qq = fmaf(qx, qx, fmaf(qy, qy, qz * qz));

    const int CH = M / SLICES;                    // 512
    const int j0 = swid * CH;                     // uniform (SGPR)

    // Exact running top-5 of d2' = |p|^2 - 2 q.p  (ascending; e0 smallest).
    float e0 = 1e30f, e1 = 1e30f, e2 = 1e30f, e3 = 1e30f, e4 = 1e30f;
    u32   i0 = 0, i1 = 0, i2 = 0, i3 = 0, i4 = 0;

    if constexpr (USE_PTS) {
        const float4* __restrict__ P = pts + (size_t)b * M + j0;  // uniform
#pragma unroll 4
        for (int j = 0; j < CH; ++j) {
            const float4 p = P[j];                // s_load_dwordx4 (scalar pipe)
            float t = qx * p.x;
            t = fmaf(qy, p.y, t);
            t = fmaf(qz, p.z, t);
            float c = fmaf(-2.0f, t, p.w);        // d2' (qq deferred)
            u32 ci = (u32)(j0 + j);
            CE_FULL(e0, i0, c, ci)
            CE_FULL(e1, i1, c, ci)
            CE_FULL(e2, i2, c, ci)
            CE_FULL(e3, i3, c, ci)
            CE_LAST(e4, i4, c, ci)
        }
    } else {
        const float* __restrict__ sb = sxyz + (size_t)b * 3 * M;  // uniform
#pragma unroll 4
        for (int j = 0; j < CH; ++j) {
            const float px = sb[j0 + j] * inv;            // s_load + v_mul
            const float py = sb[M + j0 + j] * inv;
            const float pz = sb[2 * M + j0 + j] * inv;
            const float pw = fmaf(px, px, fmaf(py, py, pz * pz));
            float t = qx * px;
            t = fmaf(qy, py, t);
            t = fmaf(qz, pz, t);
            float c = fmaf(-2.0f, t, pw);
            u32 ci = (u32)(j0 + j);
            CE_FULL(e0, i0, c, ci)
            CE_FULL(e1, i1, c, ci)
            CE_FULL(e2, i2, c, ci)
            CE_FULL(e3, i3, c, ci)
            CE_LAST(e4, i4, c, ci)
        }
    }

    sval_d[(wid * KNN + 0) * 64 + lane] = e0;  sval_i[(wid * KNN + 0) * 64 + lane] = i0;
    sval_d[(wid * KNN + 1) * 64 + lane] = e1;  sval_i[(wid * KNN + 1) * 64 + lane] = i1;
    sval_d[(wid * KNN + 2) * 64 + lane] = e2;  sval_i[(wid * KNN + 2) * 64 + lane] = i2;
    sval_d[(wid * KNN + 3) * 64 + lane] = e3;  sval_i[(wid * KNN + 3) * 64 + lane] = i3;
    sval_d[(wid * KNN + 4) * 64 + lane] = e4;  sval_i[(wid * KNN + 4) * 64 + lane] = i4;
    __syncthreads();

    // ---- wave 0: merge 8x5 -> top-5, exact epilogue ----
    if (wid == 0) {
        float m0 = 1e30f, m1 = 1e30f, m2 = 1e30f, m3 = 1e30f, m4 = 1e30f;
        u32   g0 = 0, g1 = 0, g2 = 0, g3 = 0, g4 = 0;
        // Insert in increasing wave order: incumbents (earlier w = lower idx)
        // win ties -> global lowest-index tie-break matches jax top_k.
#pragma unroll
        for (int w = 0; w < SLICES; ++w) {
#pragma unroll
            for (int k = 0; k < KNN; ++k) {
                float c = sval_d[(w * KNN + k) * 64 + lane];
                u32  ci = sval_i[(w * KNN + k) * 64 + lane];
                CE_FULL(m0, g0, c, ci)
                CE_FULL(m1, g1, c, ci)
                CE_FULL(m2, g2, c, ci)
                CE_FULL(m3, g3, c, ci)
                CE_LAST(m4, g4, c, ci)
            }
        }

        // exact distances: sq = d2' + qq, clamp, sqrt (m0..m4 ascending)
        const float d0 = sqrtf(fmaxf(m0 + qq, 1e-12f));
        const float d1 = sqrtf(fmaxf(m1 + qq, 1e-12f));
        const float d2 = sqrtf(fmaxf(m2 + qq, 1e-12f));
        const float d3 = sqrtf(fmaxf(m3 + qq, 1e-12f));
        const float d4 = sqrtf(fmaxf(m4 + qq, 1e-12f));
        const float w0 = expf(d0 - d0);
        const float w1 = expf(d0 - d1);
        const float w2 = expf(d0 - d2);
        const float w3 = expf(d0 - d3);
        const float w4 = expf(d0 - d4);
        const float inv_wsum = 1.0f / (w0 + w1 + w2 + w3 + w4);

        const float* fb = sflow + (size_t)b * 3 * M;
        float ax = 0.f, ay = 0.f, az = 0.f;
        ax = fmaf(w0, fb[g0], ax); ay = fmaf(w0, fb[M + g0], ay); az = fmaf(w0, fb[2 * M + g0], az);
        ax = fmaf(w1, fb[g1], ax); ay = fmaf(w1, fb[M + g1], ay); az = fmaf(w1, fb[2 * M + g1], az);
        ax = fmaf(w2, fb[g2], ax); ay = fmaf(w2, fb[M + g2], ay); az = fmaf(w2, fb[2 * M + g2], az);
        ax = fmaf(w3, fb[g3], ax); ay = fmaf(w3, fb[M + g3], ay); az = fmaf(w3, fb[2 * M + g3], az);
        ax = fmaf(w4, fb[g4], ax); ay = fmaf(w4, fb[M + g4], ay); az = fmaf(w4, fb[2 * M + g4], az);

        float* ob = out + (size_t)b * 3 * N;
        ob[n]         = ax * inv_wsum;
        ob[N + n]     = ay * inv_wsum;
        ob[2 * N + n] = az * inv_wsum;
    }
}

extern "C" void kernel_launch(void* const* d_in, const int* in_sizes, int n_in,
                              void* d_out, int out_size, void* d_ws, size_t ws_size,
                              hipStream_t stream) {
    const float* xyz   = (const float*)d_in[0];
    const float* sxyz  = (const float*)d_in[1];
    const float* sflow = (const float*)d_in[2];
    const int*   rf    = (const int*)d_in[3];
    // d_in[4] = K; fixed at 5 (KNN).

    const int B = 4;
    const int N = in_sizes[0] / (3 * B);    // 16384
    const int M = in_sizes[1] / (3 * B);    // 4096
    float* out = (float*)d_out;

    const dim3 grid(B * (N / 64));          // 1024 blocks
    const dim3 block(BLOCK);

    const size_t need = (size_t)B * M * sizeof(float4);
    if (ws_size >= need) {
        float4* pts = (float4*)d_ws;
        prep_kernel<<<dim3((B * M + 255) / 256), dim3(256), 0, stream>>>(sxyz, rf, pts, M, B * M);
        knn_kernel<true><<<grid, block, 0, stream>>>(xyz, sxyz, sflow, rf, pts, out, N, M);
    } else {
        knn_kernel<false><<<grid, block, 0, stream>>>(xyz, sxyz, sflow, rf, nullptr, out, N, M);
    }
}